// Round 5
// baseline (11742.556 us; speedup 1.0000x reference)
//
#include <hip/hip_runtime.h>
#include <hip/hip_bf16.h>
#include <hip/hip_cooperative_groups.h>
#include <math.h>

namespace cg = cooperative_groups;

#define DEVI static __device__ __forceinline__

namespace {
constexpr int B = 32, T = 512, H = 1024, E = 300, V = 32000, S = 50;
constexpr int KX = E + H;       // 1324
constexpr int K0 = 2368;        // KX + H + 20 zero-pad  (74 * 32)
constexpr int K1 = 2048;        // H + H                 (64 * 32)
constexpr int MG = V + H;       // 33024 = generator rows + attn-left rows
constexpr int NPB = (H / 64) * (B * T / 64);  // 16*256 = 4096 encproj tasks
}

typedef __bf16 bf16x8 __attribute__((ext_vector_type(8)));
typedef float f32x4 __attribute__((ext_vector_type(4)));

struct P {
  const float *enc_out, *enc_h, *enc_c, *embedding, *attn_W, *attn_b, *vvec;
  const float *Wih0, *Whh0, *bih0, *bhh0, *Wih1, *Whh1, *bih1, *bhh1, *genW, *genb;
  const int* question;
  float* out;
  unsigned short *Wbig, *Wc0, *Wc1, *encb, *encp, *Wr;
  float *bcomb0, *bcomb1, *cbuf;
  unsigned short *xc0a, *xc0b, *xc1a, *xc1b, *hgen;
  float *hidproj, *scores, *logits, *part;
};

DEVI float bf2f(unsigned short u) { union { unsigned int i; float f; } v; v.i = (unsigned int)u << 16; return v.f; }
DEVI unsigned short f2bf(float f) {
  union { float f; unsigned int i; } v; v.f = f;
  unsigned int x = v.i;
  return (unsigned short)((x + 0x7fffu + ((x >> 16) & 1u)) >> 16);
}
#if __has_builtin(__builtin_amdgcn_rcpf)
DEVI float frcp(float x) { return __builtin_amdgcn_rcpf(x); }
#else
DEVI float frcp(float x) { return 1.0f / x; }
#endif
DEVI float sigm(float x) { return frcp(1.0f + __expf(-x)); }
DEVI float tanh_(float x) { return 1.0f - 2.0f * frcp(__expf(2.0f * x) + 1.0f); }

// ===== Phase A: all casts + bias + init (grid-stride elementwise) ==========
DEVI void phaseA(const P& p, int bid, int nb, int tid) {
  const int gsz = nb * 256;
  const int g = bid * 256 + tid;
  // genW rows then attn-left rows -> Wbig bf16 [MG][H]
  for (size_t it = g; it < (size_t)MG * H / 4; it += gsz) {
    size_t i4 = it * 4;
    int row = (int)(i4 >> 10), k = (int)(i4 & 1023);
    const float* src = row < V ? &p.genW[((size_t)row << 10) + k]
                               : &p.attn_W[(size_t)(row - V) * (2 * H) + k];
    float4 v = *(const float4*)src;
    ushort4 o; o.x = f2bf(v.x); o.y = f2bf(v.y); o.z = f2bf(v.z); o.w = f2bf(v.w);
    *(ushort4*)&p.Wbig[i4] = o;
  }
  // lstm0 weights, gate-interleaved rows m = n*4+g, K0 with zero pad
  for (int m = bid; m < 4096; m += nb) {
    int gg = m & 3, n = m >> 2, srow = gg * H + n;
    for (int i = tid; i < K0 / 4; i += 256) {
      int k = i * 4;
      float4 v;
      if (k < KX) v = *(const float4*)&p.Wih0[(size_t)srow * KX + k];
      else if (k < KX + H) v = *(const float4*)&p.Whh0[(size_t)srow * H + (k - KX)];
      else v = make_float4(0.f, 0.f, 0.f, 0.f);
      ushort4 o; o.x = f2bf(v.x); o.y = f2bf(v.y); o.z = f2bf(v.z); o.w = f2bf(v.w);
      *(ushort4*)&p.Wc0[(size_t)m * K0 + k] = o;
    }
  }
  // lstm1 weights
  for (int m = bid; m < 4096; m += nb) {
    int gg = m & 3, n = m >> 2, srow = gg * H + n;
    for (int i = tid; i < K1 / 4; i += 256) {
      int k = i * 4;
      float4 v = (k < H) ? *(const float4*)&p.Wih1[(size_t)srow * H + k]
                         : *(const float4*)&p.Whh1[(size_t)srow * H + (k - H)];
      ushort4 o; o.x = f2bf(v.x); o.y = f2bf(v.y); o.z = f2bf(v.z); o.w = f2bf(v.w);
      *(ushort4*)&p.Wc1[(size_t)m * K1 + k] = o;
    }
  }
  // attn_W right half -> Wr bf16 [H][H]
  for (size_t it = g; it < (size_t)H * H / 4; it += gsz) {
    size_t i4 = it * 4;
    int n = (int)(i4 >> 10), k = (int)(i4 & 1023);
    float4 v = *(const float4*)&p.attn_W[(size_t)n * (2 * H) + H + k];
    ushort4 o; o.x = f2bf(v.x); o.y = f2bf(v.y); o.z = f2bf(v.z); o.w = f2bf(v.w);
    *(ushort4*)&p.Wr[i4] = o;
  }
  // enc_out -> bf16
  for (size_t it = g; it < (size_t)B * T * H / 4; it += gsz) {
    size_t i4 = it * 4;
    float4 v = *(const float4*)&p.enc_out[i4];
    ushort4 o; o.x = f2bf(v.x); o.y = f2bf(v.y); o.z = f2bf(v.z); o.w = f2bf(v.w);
    *(ushort4*)&p.encb[i4] = o;
  }
  // combined biases
  for (int idx = g; idx < 8192; idx += gsz) {
    if (idx < 4096) { int gg = idx & 3, n = idx >> 2; p.bcomb0[idx] = p.bih0[gg * H + n] + p.bhh0[gg * H + n]; }
    else { int m = idx - 4096; int gg = m & 3, n = m >> 2; p.bcomb1[m] = p.bih1[gg * H + n] + p.bhh1[gg * H + n]; }
  }
  // initial state merge + zero pad
  for (int idx = g; idx < 2 * B * H + 2 * B * 20; idx += gsz) {
    if (idx < 2 * B * H) {
      int l = idx >> 15, r = idx & 32767, b = r >> 10, hh = r & 1023;
      int half = hh >> 9, hr = hh & 511;
      int src = (2 * l + half) * B * (H / 2) + b * (H / 2) + hr;
      p.cbuf[idx] = p.enc_c[src];
      unsigned short hb = f2bf(p.enc_h[src]);
      if (l == 0) p.xc0a[(size_t)b * K0 + KX + hh] = hb;
      else { p.xc1a[(size_t)b * K1 + H + hh] = hb; p.hgen[(size_t)b * H + hh] = hb; }
    } else {
      int j = idx - 2 * B * H;
      int pp2 = j / (B * 20), rr = j % (B * 20), b = rr / 20, kk = rr % 20;
      (pp2 ? p.xc0b : p.xc0a)[(size_t)b * K0 + KX + H + kk] = 0;
    }
  }
}

// ===== MFMA GEMM core: 16 rows x 32 batch per wave =========================
template <int K>
DEVI void gemm_tile(const unsigned short* __restrict__ W, const unsigned short* __restrict__ X,
                    int m0w, int lane, f32x4& acc0, f32x4& acc1) {
  const unsigned short* Wp = W + (size_t)(m0w + (lane & 15)) * K + (lane >> 4) * 8;
  const unsigned short* Xp = X + (size_t)(lane & 15) * K + (lane >> 4) * 8;
#pragma unroll 4
  for (int k0 = 0; k0 < K; k0 += 32) {
    bf16x8 a  = *(const bf16x8*)(Wp + k0);
    bf16x8 b0 = *(const bf16x8*)(Xp + k0);
    bf16x8 b1 = *(const bf16x8*)(Xp + 16 * K + k0);
    acc0 = __builtin_amdgcn_mfma_f32_16x16x32_bf16(a, b0, acc0, 0, 0, 0);
    acc1 = __builtin_amdgcn_mfma_f32_16x16x32_bf16(a, b1, acc1, 0, 0, 0);
  }
}

// ===== Phase B tasks: enc projection + initial hidproj =====================
// task in [0, NPB): n-block = task & 15, m-block = task >> 4  (16 x 256)
DEVI void encproj_task(const P& p, int task, int tid) {
  int wv = tid >> 6, lane = tid & 63;
  int n0w = (task & 15) * 64 + wv * 16;
  int m0 = (task >> 4) * 64;
  const unsigned short* Wp = p.Wr + (size_t)(n0w + (lane & 15)) * H + (lane >> 4) * 8;
  const unsigned short* Xp = p.encb + (size_t)(m0 + (lane & 15)) * H + (lane >> 4) * 8;
  f32x4 acc[4] = {{0.f,0.f,0.f,0.f},{0.f,0.f,0.f,0.f},{0.f,0.f,0.f,0.f},{0.f,0.f,0.f,0.f}};
#pragma unroll 2
  for (int k0 = 0; k0 < H; k0 += 32) {
    bf16x8 a = *(const bf16x8*)(Wp + k0);
#pragma unroll
    for (int gq = 0; gq < 4; gq++) {
      bf16x8 b = *(const bf16x8*)(Xp + (size_t)gq * 16 * H + k0);
      acc[gq] = __builtin_amdgcn_mfma_f32_16x16x32_bf16(a, b, acc[gq], 0, 0, 0);
    }
  }
  int nbx = n0w + (lane >> 4) * 4;
  f32x4 bi = *(const f32x4*)&p.attn_b[nbx];
#pragma unroll
  for (int gq = 0; gq < 4; gq++) {
    int m = m0 + gq * 16 + (lane & 15);
    f32x4 o = acc[gq] + bi;
    ushort4 ob; ob.x = f2bf(o[0]); ob.y = f2bf(o[1]); ob.z = f2bf(o[2]); ob.w = f2bf(o[3]);
    *(ushort4*)&p.encp[(size_t)m * H + nbx] = ob;
  }
}

DEVI void hidproj0_task(const P& p, int task, int tid) {
  int wv = tid >> 6, lane = tid & 63;
  int m0w = task * 64 + wv * 16;
  f32x4 a0 = {0.f, 0.f, 0.f, 0.f}, a1 = a0;
  gemm_tile<1024>(p.Wbig + (size_t)V * H, p.hgen, m0w, lane, a0, a1);
  int r0 = m0w + (lane >> 4) * 4, b = lane & 15;
  *(f32x4*)&p.hidproj[(size_t)b * H + r0] = a0;
  *(f32x4*)&p.hidproj[(size_t)(b + 16) * H + r0] = a1;
}

// ===== P1 tasks: scores, lsB(prev), embedding gather =======================
DEVI void scores_task(const P& p, int task, int tid) {
  int wid = task * 4 + (tid >> 6);
  int lane = tid & 63;
  int b = wid >> 9;
  const unsigned short* ep = p.encp + (size_t)wid * H;
  const float* hp = p.hidproj + (size_t)b * H;
  float acc = 0.f;
#pragma unroll
  for (int i = 0; i < 2; i++) {
    int base = i * 512 + lane * 8;
    uint4 u = *(const uint4*)&ep[base];
    float4 h0 = *(const float4*)&hp[base];
    float4 h1 = *(const float4*)&hp[base + 4];
    float4 v0 = *(const float4*)&p.vvec[base];
    float4 v1 = *(const float4*)&p.vvec[base + 4];
    acc += v0.x * tanh_(bf2f((unsigned short)(u.x & 0xffff)) + h0.x);
    acc += v0.y * tanh_(bf2f((unsigned short)(u.x >> 16)) + h0.y);
    acc += v0.z * tanh_(bf2f((unsigned short)(u.y & 0xffff)) + h0.z);
    acc += v0.w * tanh_(bf2f((unsigned short)(u.y >> 16)) + h0.w);
    acc += v1.x * tanh_(bf2f((unsigned short)(u.z & 0xffff)) + h1.x);
    acc += v1.y * tanh_(bf2f((unsigned short)(u.z >> 16)) + h1.y);
    acc += v1.z * tanh_(bf2f((unsigned short)(u.w & 0xffff)) + h1.z);
    acc += v1.w * tanh_(bf2f((unsigned short)(u.w >> 16)) + h1.w);
  }
#pragma unroll
  for (int off = 32; off; off >>= 1) acc += __shfl_xor(acc, off, 64);
  if (lane == 0) p.scores[wid] = acc;
}

DEVI void lsB_task(const P& p, int idx, int tid, int s) {
  __shared__ float red[256];
  __syncthreads();
  int b = idx >> 3, ch = idx & 7;
  float ssum = 0.f;
  for (int i = tid; i < V / 64; i += 256) ssum += p.part[i * 32 + b];
  red[tid] = ssum; __syncthreads();
  for (int st = 128; st; st >>= 1) { if (tid < st) red[tid] += red[tid + st]; __syncthreads(); }
  float lse = __logf(red[0]);
  const float* L = p.logits + (size_t)b * V + ch * 4000;
  float* O = p.out + ((size_t)b * S + s) * V + ch * 4000;
  for (int i = tid; i < 1000; i += 256) {
    float4 v = ((const float4*)L)[i];
    ((float4*)O)[i] = make_float4(v.x - lse, v.y - lse, v.z - lse, v.w - lse);
  }
}

DEVI void emb_task(const P& p, int b, int tid, int s, unsigned short* xc) {
  int tok = p.question[b * S + s];
  for (int e = tid; e < E; e += 256)
    xc[(size_t)b * K0 + e] = f2bf(p.embedding[(size_t)tok * E + e]);
}

// ===== P2: softmax + ctx ===================================================
DEVI void ctx_task(const P& p, int task, int tid, unsigned short* xc) {
  __shared__ float aw[T];
  __shared__ float red[256];
  __syncthreads();
  int b = task >> 4, y = task & 15;
  float s0 = p.scores[b * T + tid], s1 = p.scores[b * T + 256 + tid];
  float m = fmaxf(s0, s1);
  red[tid] = m; __syncthreads();
  for (int st = 128; st; st >>= 1) { if (tid < st) red[tid] = fmaxf(red[tid], red[tid + st]); __syncthreads(); }
  m = red[0]; __syncthreads();
  float e0 = __expf(s0 - m), e1 = __expf(s1 - m);
  aw[tid] = e0; aw[tid + 256] = e1;
  red[tid] = e0 + e1; __syncthreads();
  for (int st = 128; st; st >>= 1) { if (tid < st) red[tid] += red[tid + st]; __syncthreads(); }
  float inv = frcp(red[0]);
  __syncthreads();
  int wv = tid >> 6, l = tid & 63;
  int q = l & 15, tp = l >> 4;
  const unsigned short* eb = p.encb + (size_t)b * T * H + y * 64 + q * 4;
  float a0 = 0.f, a1 = 0.f, a2 = 0.f, a3 = 0.f;
  for (int it = 0; it < 32; it++) {
    int t = it * 16 + wv * 4 + tp;
    uint2 u = *(const uint2*)&eb[(size_t)t * H];
    float w = aw[t];
    a0 += w * bf2f((unsigned short)(u.x & 0xffff));
    a1 += w * bf2f((unsigned short)(u.x >> 16));
    a2 += w * bf2f((unsigned short)(u.y & 0xffff));
    a3 += w * bf2f((unsigned short)(u.y >> 16));
  }
  a0 += __shfl_xor(a0, 16, 64); a0 += __shfl_xor(a0, 32, 64);
  a1 += __shfl_xor(a1, 16, 64); a1 += __shfl_xor(a1, 32, 64);
  a2 += __shfl_xor(a2, 16, 64); a2 += __shfl_xor(a2, 32, 64);
  a3 += __shfl_xor(a3, 16, 64); a3 += __shfl_xor(a3, 32, 64);
  __syncthreads();
  if (tp == 0) {
    red[wv * 64 + q * 4 + 0] = a0; red[wv * 64 + q * 4 + 1] = a1;
    red[wv * 64 + q * 4 + 2] = a2; red[wv * 64 + q * 4 + 3] = a3;
  }
  __syncthreads();
  if (tid < 64) {
    float val = (red[tid] + red[64 + tid] + red[128 + tid] + red[192 + tid]) * inv;
    xc[(size_t)b * K0 + E + y * 64 + tid] = f2bf(val);
  }
}

// ===== P3/P4: fused LSTM layer ============================================
template <int K>
DEVI void lstm_task(const unsigned short* __restrict__ W, const unsigned short* __restrict__ X,
                    const float* __restrict__ bcomb, float* __restrict__ c,
                    unsigned short* __restrict__ hA, int ldA_, int offA,
                    unsigned short* __restrict__ hB, int ldB_, int offB,
                    int task, int tid) {
  __shared__ f32x4 red[4][64][2];
  __syncthreads();
  int wv = tid >> 6, lane = tid & 63;
  int m0w = task * 16;
  const unsigned short* Wp = W + (size_t)(m0w + (lane & 15)) * K + (lane >> 4) * 8;
  const unsigned short* Xp = X + (size_t)(lane & 15) * K + (lane >> 4) * 8;
  f32x4 acc0 = {0.f, 0.f, 0.f, 0.f}, acc1 = acc0;
#pragma unroll 2
  for (int k0 = wv * 32; k0 < K; k0 += 128) {
    bf16x8 a  = *(const bf16x8*)(Wp + k0);
    bf16x8 b0 = *(const bf16x8*)(Xp + k0);
    bf16x8 b1 = *(const bf16x8*)(Xp + 16 * K + k0);
    acc0 = __builtin_amdgcn_mfma_f32_16x16x32_bf16(a, b0, acc0, 0, 0, 0);
    acc1 = __builtin_amdgcn_mfma_f32_16x16x32_bf16(a, b1, acc1, 0, 0, 0);
  }
  red[wv][lane][0] = acc0;
  red[wv][lane][1] = acc1;
  __syncthreads();
  if (wv == 0) {
    acc0 = red[0][lane][0] + red[1][lane][0] + red[2][lane][0] + red[3][lane][0];
    acc1 = red[0][lane][1] + red[1][lane][1] + red[2][lane][1] + red[3][lane][1];
    int r0 = m0w + (lane >> 4) * 4;
    int n = r0 >> 2;
    f32x4 bi = *(const f32x4*)&bcomb[r0];
#pragma unroll
    for (int f = 0; f < 2; f++) {
      f32x4 g = f ? acc1 : acc0;
      int b = (lane & 15) + f * 16;
      float gi = g[0] + bi[0], gf = g[1] + bi[1];
      float gg = g[2] + bi[2], go = g[3] + bi[3];
      float cp = c[(size_t)b * H + n];
      float c2 = sigm(gf) * cp + sigm(gi) * tanh_(gg);
      c[(size_t)b * H + n] = c2;
      unsigned short hb = f2bf(sigm(go) * tanh_(c2));
      hA[(size_t)b * ldA_ + offA + n] = hb;
      hB[(size_t)b * ldB_ + offB + n] = hb;
    }
  }
}

// ===== P5: generator (+hidproj rows) with expsum partials ==================
DEVI void gen_task(const P& p, int task, int tid) {
  __shared__ float esum[4][32];
  __syncthreads();
  int wv = tid >> 6, lane = tid & 63;
  int m0w = task * 64 + wv * 16;
  f32x4 acc0 = {0.f, 0.f, 0.f, 0.f}, acc1 = acc0;
  gemm_tile<1024>(p.Wbig, p.hgen, m0w, lane, acc0, acc1);
  int r0 = m0w + (lane >> 4) * 4;
  int b = lane & 15;
  float s0 = 0.f, s1 = 0.f;
  if (r0 < V) {
    f32x4 bi = *(const f32x4*)&p.genb[r0];
    f32x4 o0 = acc0 + bi, o1 = acc1 + bi;
    *(f32x4*)&p.logits[(size_t)b * V + r0] = o0;
    *(f32x4*)&p.logits[(size_t)(b + 16) * V + r0] = o1;
    s0 = __expf(o0[0]) + __expf(o0[1]) + __expf(o0[2]) + __expf(o0[3]);
    s1 = __expf(o1[0]) + __expf(o1[1]) + __expf(o1[2]) + __expf(o1[3]);
  } else {
    int r = r0 - V;
    *(f32x4*)&p.hidproj[(size_t)b * H + r] = acc0;
    *(f32x4*)&p.hidproj[(size_t)(b + 16) * H + r] = acc1;
  }
  if (task < V / 64) {
    s0 += __shfl_xor(s0, 16, 64); s0 += __shfl_xor(s0, 32, 64);
    s1 += __shfl_xor(s1, 16, 64); s1 += __shfl_xor(s1, 32, 64);
    if (lane < 16) { esum[wv][lane] = s0; esum[wv][lane + 16] = s1; }
    __syncthreads();
    if (tid < 32)
      p.part[task * 32 + tid] =
          esum[0][tid] + esum[1][tid] + esum[2][tid] + esum[3][tid];
  }
}

// ===== step-phase drivers (shared by mega + fallback wrappers) =============
DEVI void runP1(const P& p, int s, int bid, int nb, int tid) {
  unsigned short* xc0c = (s & 1) ? p.xc0b : p.xc0a;
  for (int task = bid; task < 4096 + 256 + 32; task += nb) {
    if (task < 4096) scores_task(p, task, tid);
    else if (task < 4352) { if (s > 0) lsB_task(p, task - 4096, tid, s - 1); }
    else emb_task(p, task - 4352, tid, s, xc0c);
  }
}
DEVI void runP2(const P& p, int s, int bid, int nb, int tid) {
  unsigned short* xc0c = (s & 1) ? p.xc0b : p.xc0a;
  for (int task = bid; task < 512; task += nb) ctx_task(p, task, tid, xc0c);
}
DEVI void runP3(const P& p, int s, int bid, int nb, int tid) {
  unsigned short* xc0c = (s & 1) ? p.xc0b : p.xc0a;
  unsigned short* xc0n = (s & 1) ? p.xc0a : p.xc0b;
  unsigned short* xc1c = (s & 1) ? p.xc1b : p.xc1a;
  for (int task = bid; task < 256; task += nb)
    lstm_task<K0>(p.Wc0, xc0c, p.bcomb0, p.cbuf, xc0n, K0, KX, xc1c, K1, 0, task, tid);
}
DEVI void runP4(const P& p, int s, int bid, int nb, int tid) {
  unsigned short* xc1c = (s & 1) ? p.xc1b : p.xc1a;
  unsigned short* xc1n = (s & 1) ? p.xc1a : p.xc1b;
  for (int task = bid; task < 256; task += nb)
    lstm_task<K1>(p.Wc1, xc1c, p.bcomb1, p.cbuf + B * H, xc1n, K1, H, p.hgen, H, 0, task, tid);
}
DEVI void runP5(const P& p, int s, int bid, int nb, int tid) {
  for (int task = bid; task < MG / 64; task += nb) gen_task(p, task, tid);
}
DEVI void runPB(const P& p, int bid, int nb, int tid) {
  for (int task = bid; task < NPB + 16; task += nb) {
    if (task < NPB) encproj_task(p, task, tid);
    else hidproj0_task(p, task - NPB, tid);
  }
}

// ===== the persistent cooperative kernel ===================================
__global__ __launch_bounds__(256, 2) void mega(P p) {
  cg::grid_group grid = cg::this_grid();
  const int bid = blockIdx.x, nb = gridDim.x, tid = threadIdx.x;
  phaseA(p, bid, nb, tid);
  grid.sync();
  runPB(p, bid, nb, tid);
  grid.sync();
  for (int s = 0; s < S; s++) {
    runP1(p, s, bid, nb, tid);
    grid.sync();
    runP2(p, s, bid, nb, tid);
    grid.sync();
    runP3(p, s, bid, nb, tid);
    grid.sync();
    runP4(p, s, bid, nb, tid);
    grid.sync();
    runP5(p, s, bid, nb, tid);
    grid.sync();
  }
  for (int task = bid; task < 256; task += nb) lsB_task(p, task, tid, S - 1);
}

// ===== fallback wrappers (plain launches, same phase code) =================
__global__ __launch_bounds__(256, 2) void k_wA(P p)  { phaseA(p, blockIdx.x, gridDim.x, threadIdx.x); }
__global__ __launch_bounds__(256, 2) void k_wB(P p)  { runPB(p, blockIdx.x, gridDim.x, threadIdx.x); }
__global__ __launch_bounds__(256, 2) void k_wP1(P p, int s) { runP1(p, s, blockIdx.x, gridDim.x, threadIdx.x); }
__global__ __launch_bounds__(256, 2) void k_wP2(P p, int s) { runP2(p, s, blockIdx.x, gridDim.x, threadIdx.x); }
__global__ __launch_bounds__(256, 2) void k_wP3(P p, int s) { runP3(p, s, blockIdx.x, gridDim.x, threadIdx.x); }
__global__ __launch_bounds__(256, 2) void k_wP4(P p, int s) { runP4(p, s, blockIdx.x, gridDim.x, threadIdx.x); }
__global__ __launch_bounds__(256, 2) void k_wP5(P p, int s) { runP5(p, s, blockIdx.x, gridDim.x, threadIdx.x); }
__global__ __launch_bounds__(256, 2) void k_wF(P p) {
  for (int task = blockIdx.x; task < 256; task += gridDim.x) lsB_task(p, task, threadIdx.x, S - 1);
}

// ===========================================================================
extern "C" void kernel_launch(void* const* d_in, const int* in_sizes, int n_in,
                              void* d_out, int out_size, void* d_ws, size_t ws_size,
                              hipStream_t stream) {
  P p;
  p.enc_out   = (const float*)d_in[0];
  p.enc_h     = (const float*)d_in[1];
  p.enc_c     = (const float*)d_in[2];
  p.embedding = (const float*)d_in[3];
  p.attn_W    = (const float*)d_in[4];
  p.attn_b    = (const float*)d_in[5];
  p.vvec      = (const float*)d_in[6];
  p.Wih0      = (const float*)d_in[7];
  p.Whh0      = (const float*)d_in[8];
  p.bih0      = (const float*)d_in[9];
  p.bhh0      = (const float*)d_in[10];
  p.Wih1      = (const float*)d_in[11];
  p.Whh1      = (const float*)d_in[12];
  p.bih1      = (const float*)d_in[13];
  p.bhh1      = (const float*)d_in[14];
  p.genW      = (const float*)d_in[15];
  p.genb      = (const float*)d_in[16];
  p.question  = (const int*)d_in[17];
  p.out       = (float*)d_out;

  char* w = (char*)d_ws;
  auto alloc = [&](size_t bytes) { char* r = w; w += (bytes + 255) & ~(size_t)255; return r; };
  p.Wbig  = (unsigned short*)alloc((size_t)MG * H * 2);
  p.Wc0   = (unsigned short*)alloc((size_t)4096 * K0 * 2);
  p.Wc1   = (unsigned short*)alloc((size_t)4096 * K1 * 2);
  p.encb  = (unsigned short*)alloc((size_t)B * T * H * 2);
  p.encp  = (unsigned short*)alloc((size_t)B * T * H * 2);
  p.Wr    = (unsigned short*)alloc((size_t)H * H * 2);
  p.bcomb0 = (float*)alloc(4096 * 4);
  p.bcomb1 = (float*)alloc(4096 * 4);
  p.cbuf   = (float*)alloc((size_t)2 * B * H * 4);
  p.xc0a  = (unsigned short*)alloc((size_t)B * K0 * 2);
  p.xc0b  = (unsigned short*)alloc((size_t)B * K0 * 2);
  p.xc1a  = (unsigned short*)alloc((size_t)B * K1 * 2);
  p.xc1b  = (unsigned short*)alloc((size_t)B * K1 * 2);
  p.hgen  = (unsigned short*)alloc((size_t)B * H * 2);
  p.hidproj = (float*)alloc((size_t)B * H * 4);
  p.scores  = (float*)alloc((size_t)B * T * 4);
  p.logits  = (float*)alloc((size_t)B * V * 4);
  p.part    = (float*)alloc((size_t)(V / 64) * 32 * 4);

  int mab = 0;
  if (hipOccupancyMaxActiveBlocksPerMultiprocessor(&mab, mega, 256, 0) != hipSuccess || mab < 1)
    mab = 1;
  int grid = (mab >= 2) ? 512 : 256;

  void* args[] = {(void*)&p};
  hipError_t e = hipLaunchCooperativeKernel(mega, dim3(grid), dim3(256), args, 0, stream);
  if (e != hipSuccess) {
    (void)hipGetLastError();  // clear error, use fallback path
    k_wA<<<512, 256, 0, stream>>>(p);
    k_wB<<<512, 256, 0, stream>>>(p);
    for (int s = 0; s < S; s++) {
      k_wP1<<<512, 256, 0, stream>>>(p, s);
      k_wP2<<<512, 256, 0, stream>>>(p, s);
      k_wP3<<<512, 256, 0, stream>>>(p, s);
      k_wP4<<<512, 256, 0, stream>>>(p, s);
      k_wP5<<<512, 256, 0, stream>>>(p, s);
    }
    k_wF<<<512, 256, 0, stream>>>(p);
  }
}

// Round 7
// 3957.077 us; speedup vs baseline: 2.9675x; 2.9675x over previous
//
#include <hip/hip_runtime.h>
#include <hip/hip_bf16.h>
#include <math.h>

#define DEVI static __device__ __forceinline__

namespace {
constexpr int B = 32, T = 512, H = 1024, E = 300, V = 32000, S = 50;
constexpr int KX = E + H;       // 1324
constexpr int K0 = 2368;        // KX + H + 20 zero-pad  (74 * 32)
constexpr int K1 = 2048;        // H + H                 (64 * 32)
constexpr int MG = V + H;       // 33024 = generator rows + attn-left rows
}

typedef __bf16 bf16x8 __attribute__((ext_vector_type(8)));
typedef float f32x4 __attribute__((ext_vector_type(4)));

DEVI float bf2f(unsigned short u) { union { unsigned int i; float f; } v; v.i = (unsigned int)u << 16; return v.f; }
DEVI unsigned short f2bf(float f) {
  union { float f; unsigned int i; } v; v.f = f;
  unsigned int x = v.i;
  return (unsigned short)((x + 0x7fffu + ((x >> 16) & 1u)) >> 16);
}
#if __has_builtin(__builtin_amdgcn_rcpf)
DEVI float frcp(float x) { return __builtin_amdgcn_rcpf(x); }
#else
DEVI float frcp(float x) { return 1.0f / x; }
#endif
DEVI float sigm(float x) { return frcp(1.0f + __expf(-x)); }
DEVI float tanh_(float x) { return 1.0f - 2.0f * frcp(__expf(2.0f * x) + 1.0f); }

// ===== one-time weight casts ==============================================
__global__ __launch_bounds__(256) void k_cast_gen(const float* __restrict__ genW,
    const float* __restrict__ attn_W, unsigned short* __restrict__ Wbig) {
  size_t i4 = ((size_t)blockIdx.x * 256 + threadIdx.x) * 4;
  if (i4 >= (size_t)MG * H) return;
  int row = (int)(i4 >> 10), k = (int)(i4 & 1023);
  const float* src = row < V ? &genW[((size_t)row << 10) + k]
                             : &attn_W[(size_t)(row - V) * (2 * H) + k];
  float4 v = *(const float4*)src;
  ushort4 o; o.x = f2bf(v.x); o.y = f2bf(v.y); o.z = f2bf(v.z); o.w = f2bf(v.w);
  *(ushort4*)&Wbig[i4] = o;
}

__global__ __launch_bounds__(256) void k_cast_l0(const float* __restrict__ Wih,
    const float* __restrict__ Whh, unsigned short* __restrict__ Wc) {
  int m = blockIdx.x;                       // 4096 rows, m = n*4 + g
  int g = m & 3, n = m >> 2, srow = g * H + n;
  for (int i = threadIdx.x; i < K0 / 4; i += 256) {
    int k = i * 4;
    float4 v;
    if (k < KX) v = *(const float4*)&Wih[(size_t)srow * KX + k];
    else if (k < KX + H) v = *(const float4*)&Whh[(size_t)srow * H + (k - KX)];
    else v = make_float4(0.f, 0.f, 0.f, 0.f);
    ushort4 o; o.x = f2bf(v.x); o.y = f2bf(v.y); o.z = f2bf(v.z); o.w = f2bf(v.w);
    *(ushort4*)&Wc[(size_t)m * K0 + k] = o;
  }
}

__global__ __launch_bounds__(256) void k_cast_l1(const float* __restrict__ Wih,
    const float* __restrict__ Whh, unsigned short* __restrict__ Wc) {
  int m = blockIdx.x;
  int g = m & 3, n = m >> 2, srow = g * H + n;
  for (int i = threadIdx.x; i < K1 / 4; i += 256) {
    int k = i * 4;
    float4 v = (k < H) ? *(const float4*)&Wih[(size_t)srow * H + k]
                       : *(const float4*)&Whh[(size_t)srow * H + (k - H)];
    ushort4 o; o.x = f2bf(v.x); o.y = f2bf(v.y); o.z = f2bf(v.z); o.w = f2bf(v.w);
    *(ushort4*)&Wc[(size_t)m * K1 + k] = o;
  }
}

__global__ __launch_bounds__(256) void k_cast_attnr(const float* __restrict__ attn_W,
                                                    unsigned short* __restrict__ Wr) {
  size_t i4 = ((size_t)blockIdx.x * 256 + threadIdx.x) * 4;
  if (i4 >= (size_t)H * H) return;
  int n = (int)(i4 >> 10), k = (int)(i4 & 1023);
  float4 v = *(const float4*)&attn_W[(size_t)n * (2 * H) + H + k];
  ushort4 o; o.x = f2bf(v.x); o.y = f2bf(v.y); o.z = f2bf(v.z); o.w = f2bf(v.w);
  *(ushort4*)&Wr[i4] = o;
}

__global__ void k_bias(const float* bih0, const float* bhh0,
                       const float* bih1, const float* bhh1,
                       float* bc0, float* bc1) {
  int idx = blockIdx.x * 256 + threadIdx.x;
  if (idx < 4096) { int g = idx & 3, n = idx >> 2; bc0[idx] = bih0[g * H + n] + bhh0[g * H + n]; }
  else if (idx < 8192) { int m = idx - 4096; int g = m & 3, n = m >> 2; bc1[m] = bih1[g * H + n] + bhh1[g * H + n]; }
}

__global__ __launch_bounds__(256) void k_cast_enc(const float* __restrict__ src,
                                                  unsigned short* __restrict__ dst) {
  size_t i4 = ((size_t)blockIdx.x * 256 + threadIdx.x) * 4;
  if (i4 >= (size_t)B * T * H) return;
  float4 v = *(const float4*)&src[i4];
  ushort4 o; o.x = f2bf(v.x); o.y = f2bf(v.y); o.z = f2bf(v.z); o.w = f2bf(v.w);
  *(ushort4*)&dst[i4] = o;
}

// ===== initial state =======================================================
__global__ __launch_bounds__(256) void k_init(const float* __restrict__ enc_h,
    const float* __restrict__ enc_c, float* __restrict__ cbuf,
    unsigned short* __restrict__ xc0_0, unsigned short* __restrict__ xc0_1,
    unsigned short* __restrict__ xc1_0, unsigned short* __restrict__ hgen) {
  int idx = blockIdx.x * 256 + threadIdx.x;
  if (idx < 2 * B * H) {
    int l = idx >> 15, r = idx & 32767, b = r >> 10, hh = r & 1023;
    int half = hh >> 9, hr = hh & 511;
    int src = (2 * l + half) * B * (H / 2) + b * (H / 2) + hr;
    cbuf[idx] = enc_c[src];
    unsigned short hb = f2bf(enc_h[src]);
    if (l == 0) xc0_0[(size_t)b * K0 + KX + hh] = hb;
    else { xc1_0[(size_t)b * K1 + H + hh] = hb; hgen[(size_t)b * H + hh] = hb; }
  } else if (idx < 2 * B * H + 2 * B * 20) {
    int j = idx - 2 * B * H;
    int p = j / (B * 20), rr = j % (B * 20), b = rr / 20, kk = rr % 20;
    (p ? xc0_1 : xc0_0)[(size_t)b * K0 + KX + H + kk] = 0;
  }
}

// ===== one-time enc projection: MFMA bf16 GEMM =============================
__global__ __launch_bounds__(256) void k_encproj_mfma(const unsigned short* __restrict__ Wr,
    const unsigned short* __restrict__ Xb, const float* __restrict__ attn_b,
    unsigned short* __restrict__ encp) {
  int wv = threadIdx.x >> 6, lane = threadIdx.x & 63;
  int n0w = blockIdx.x * 64 + wv * 16;
  int m0 = blockIdx.y * 64;
  const unsigned short* Wp = Wr + (size_t)(n0w + (lane & 15)) * H + (lane >> 4) * 8;
  const unsigned short* Xp = Xb + (size_t)(m0 + (lane & 15)) * H + (lane >> 4) * 8;
  f32x4 acc[4] = {{0.f,0.f,0.f,0.f},{0.f,0.f,0.f,0.f},{0.f,0.f,0.f,0.f},{0.f,0.f,0.f,0.f}};
#pragma unroll 2
  for (int k0 = 0; k0 < H; k0 += 32) {
    bf16x8 a = *(const bf16x8*)(Wp + k0);
#pragma unroll
    for (int g = 0; g < 4; g++) {
      bf16x8 b = *(const bf16x8*)(Xp + (size_t)g * 16 * H + k0);
      acc[g] = __builtin_amdgcn_mfma_f32_16x16x32_bf16(a, b, acc[g], 0, 0, 0);
    }
  }
  int nb = n0w + (lane >> 4) * 4;
  f32x4 bi = *(const f32x4*)&attn_b[nb];
#pragma unroll
  for (int g = 0; g < 4; g++) {
    int m = m0 + g * 16 + (lane & 15);
    f32x4 o = acc[g] + bi;
    ushort4 ob; ob.x = f2bf(o[0]); ob.y = f2bf(o[1]); ob.z = f2bf(o[2]); ob.w = f2bf(o[3]);
    *(ushort4*)&encp[(size_t)m * H + nb] = ob;
  }
}

// ===== MFMA GEMM core: 16 rows x 32 batch per wave =========================
template <int K>
DEVI void gemm_tile(const unsigned short* __restrict__ W, const unsigned short* __restrict__ X,
                    int m0w, int lane, f32x4& acc0, f32x4& acc1) {
  const unsigned short* Wp = W + (size_t)(m0w + (lane & 15)) * K + (lane >> 4) * 8;
  const unsigned short* Xp = X + (size_t)(lane & 15) * K + (lane >> 4) * 8;
#pragma unroll 4
  for (int k0 = 0; k0 < K; k0 += 32) {
    bf16x8 a  = *(const bf16x8*)(Wp + k0);
    bf16x8 b0 = *(const bf16x8*)(Xp + k0);
    bf16x8 b1 = *(const bf16x8*)(Xp + 16 * K + k0);
    acc0 = __builtin_amdgcn_mfma_f32_16x16x32_bf16(a, b0, acc0, 0, 0, 0);
    acc1 = __builtin_amdgcn_mfma_f32_16x16x32_bf16(a, b1, acc1, 0, 0, 0);
  }
}

// generator GEMM: rows < M0 -> logits (+bias, + per-block expsum partials),
// rows >= M0 -> hidproj. part==nullptr disables the expsum path.
template <int K>
__global__ __launch_bounds__(256) void k_gemm_out(const unsigned short* __restrict__ W,
    const unsigned short* __restrict__ X, const float* __restrict__ bias, int M0,
    float* __restrict__ out0, int ld0, float* __restrict__ out1, int ld1,
    float* __restrict__ part) {
  __shared__ float esum[4][32];
  int wv = threadIdx.x >> 6, lane = threadIdx.x & 63;
  int m0w = blockIdx.x * 64 + wv * 16;
  f32x4 acc0 = {0.f, 0.f, 0.f, 0.f}, acc1 = acc0;
  gemm_tile<K>(W, X, m0w, lane, acc0, acc1);
  int r0 = m0w + (lane >> 4) * 4;
  int b = lane & 15;
  float s0 = 0.f, s1 = 0.f;
  if (r0 < M0) {
    f32x4 bi = *(const f32x4*)&bias[r0];
    f32x4 o0 = acc0 + bi, o1 = acc1 + bi;
    *(f32x4*)&out0[(size_t)b * ld0 + r0] = o0;
    *(f32x4*)&out0[(size_t)(b + 16) * ld0 + r0] = o1;
    s0 = __expf(o0[0]) + __expf(o0[1]) + __expf(o0[2]) + __expf(o0[3]);
    s1 = __expf(o1[0]) + __expf(o1[1]) + __expf(o1[2]) + __expf(o1[3]);
  } else {
    int r = r0 - M0;
    *(f32x4*)&out1[(size_t)b * ld1 + r] = acc0;
    *(f32x4*)&out1[(size_t)(b + 16) * ld1 + r] = acc1;
  }
  if (part != nullptr && blockIdx.x < V / 64) {
    s0 += __shfl_xor(s0, 16, 64); s0 += __shfl_xor(s0, 32, 64);
    s1 += __shfl_xor(s1, 16, 64); s1 += __shfl_xor(s1, 32, 64);
    if (lane < 16) { esum[wv][lane] = s0; esum[wv][lane + 16] = s1; }
    __syncthreads();
    if (threadIdx.x < 32)
      part[blockIdx.x * 32 + threadIdx.x] =
          esum[0][threadIdx.x] + esum[1][threadIdx.x] + esum[2][threadIdx.x] + esum[3][threadIdx.x];
  }
}

// LSTM: 16 rows/block, 4 waves split K (interleaved 32-chunks), LDS reduce.
template <int K>
__global__ __launch_bounds__(256) void k_gemm_lstm(const unsigned short* __restrict__ W,
    const unsigned short* __restrict__ X, const float* __restrict__ bcomb,
    float* __restrict__ c,
    unsigned short* __restrict__ hA, int ldA_, int offA,
    unsigned short* __restrict__ hB, int ldB_, int offB) {
  __shared__ f32x4 red[4][64][2];
  int wv = threadIdx.x >> 6, lane = threadIdx.x & 63;
  int m0w = blockIdx.x * 16;
  const unsigned short* Wp = W + (size_t)(m0w + (lane & 15)) * K + (lane >> 4) * 8;
  const unsigned short* Xp = X + (size_t)(lane & 15) * K + (lane >> 4) * 8;
  f32x4 acc0 = {0.f, 0.f, 0.f, 0.f}, acc1 = acc0;
#pragma unroll 2
  for (int k0 = wv * 32; k0 < K; k0 += 128) {
    bf16x8 a  = *(const bf16x8*)(Wp + k0);
    bf16x8 b0 = *(const bf16x8*)(Xp + k0);
    bf16x8 b1 = *(const bf16x8*)(Xp + 16 * K + k0);
    acc0 = __builtin_amdgcn_mfma_f32_16x16x32_bf16(a, b0, acc0, 0, 0, 0);
    acc1 = __builtin_amdgcn_mfma_f32_16x16x32_bf16(a, b1, acc1, 0, 0, 0);
  }
  red[wv][lane][0] = acc0;
  red[wv][lane][1] = acc1;
  __syncthreads();
  if (wv == 0) {
    acc0 = red[0][lane][0] + red[1][lane][0] + red[2][lane][0] + red[3][lane][0];
    acc1 = red[0][lane][1] + red[1][lane][1] + red[2][lane][1] + red[3][lane][1];
    int r0 = m0w + (lane >> 4) * 4;
    int n = r0 >> 2;
    f32x4 bi = *(const f32x4*)&bcomb[r0];
#pragma unroll
    for (int f = 0; f < 2; f++) {
      f32x4 g = f ? acc1 : acc0;
      int b = (lane & 15) + f * 16;
      float gi = g[0] + bi[0], gf = g[1] + bi[1];
      float gg = g[2] + bi[2], go = g[3] + bi[3];
      float cp = c[(size_t)b * H + n];
      float c2 = sigm(gf) * cp + sigm(gi) * tanh_(gg);
      c[(size_t)b * H + n] = c2;
      unsigned short hb = f2bf(sigm(go) * tanh_(c2));
      hA[(size_t)b * ldA_ + offA + n] = hb;
      hB[(size_t)b * ldB_ + offB + n] = hb;
    }
  }
}

// ===== P1: scores + lsB(s-1) + embedding gather ============================
// grid 4384: [0,4096) scores (4 wids/block); [4096,4352) lsB(s-1); [4352,4384) emb.
__global__ __launch_bounds__(256) void k_p1(const unsigned short* __restrict__ encp,
    const float* __restrict__ hidproj, const float* __restrict__ vvec,
    float* __restrict__ scores,
    const float* __restrict__ logits, const float* __restrict__ part,
    float* __restrict__ out,
    const float* __restrict__ embedding, const int* __restrict__ question,
    unsigned short* __restrict__ xc, int s) {
  int bx = blockIdx.x, tid = threadIdx.x;
  if (bx < 4096) {
    int wid = bx * 4 + (tid >> 6);
    int lane = tid & 63;
    int b = wid >> 9;
    const unsigned short* ep = encp + (size_t)wid * H;
    const float* hp = hidproj + (size_t)b * H;
    float acc = 0.f;
#pragma unroll
    for (int i = 0; i < 2; i++) {
      int base = i * 512 + lane * 8;
      uint4 u = *(const uint4*)&ep[base];
      float4 h0 = *(const float4*)&hp[base];
      float4 h1 = *(const float4*)&hp[base + 4];
      float4 v0 = *(const float4*)&vvec[base];
      float4 v1 = *(const float4*)&vvec[base + 4];
      acc += v0.x * tanh_(bf2f((unsigned short)(u.x & 0xffff)) + h0.x);
      acc += v0.y * tanh_(bf2f((unsigned short)(u.x >> 16)) + h0.y);
      acc += v0.z * tanh_(bf2f((unsigned short)(u.y & 0xffff)) + h0.z);
      acc += v0.w * tanh_(bf2f((unsigned short)(u.y >> 16)) + h0.w);
      acc += v1.x * tanh_(bf2f((unsigned short)(u.z & 0xffff)) + h1.x);
      acc += v1.y * tanh_(bf2f((unsigned short)(u.z >> 16)) + h1.y);
      acc += v1.z * tanh_(bf2f((unsigned short)(u.w & 0xffff)) + h1.z);
      acc += v1.w * tanh_(bf2f((unsigned short)(u.w >> 16)) + h1.w);
    }
#pragma unroll
    for (int off = 32; off; off >>= 1) acc += __shfl_xor(acc, off, 64);
    if (lane == 0) scores[wid] = acc;
  } else if (bx < 4352) {
    if (s == 0) return;
    __shared__ float red[256];
    int idx = bx - 4096;
    int b = idx >> 3, ch = idx & 7;
    float ssum = 0.f;
    for (int i = tid; i < V / 64; i += 256) ssum += part[i * 32 + b];
    red[tid] = ssum; __syncthreads();
    for (int st = 128; st; st >>= 1) { if (tid < st) red[tid] += red[tid + st]; __syncthreads(); }
    float lse = __logf(red[0]);
    const float* L = logits + (size_t)b * V + ch * 4000;
    float* O = out + ((size_t)b * S + (s - 1)) * V + ch * 4000;
    for (int i = tid; i < 1000; i += 256) {
      float4 v = ((const float4*)L)[i];
      ((float4*)O)[i] = make_float4(v.x - lse, v.y - lse, v.z - lse, v.w - lse);
    }
  } else {
    int b = bx - 4352;
    int tok = question[b * S + s];
    for (int e = tid; e < E; e += 256)
      xc[(size_t)b * K0 + e] = f2bf(embedding[(size_t)tok * E + e]);
  }
}

// ===== ctx: softmax over T + weighted sum of enc columns ===================
__global__ __launch_bounds__(256) void k_ctx(const float* __restrict__ scores,
    const unsigned short* __restrict__ enc_bf, unsigned short* __restrict__ xc) {
  int b = blockIdx.x, y = blockIdx.y, tid = threadIdx.x;
  __shared__ float aw[T];
  __shared__ float red[256];
  float s0 = scores[b * T + tid], s1 = scores[b * T + 256 + tid];
  float m = fmaxf(s0, s1);
  red[tid] = m; __syncthreads();
  for (int st = 128; st; st >>= 1) { if (tid < st) red[tid] = fmaxf(red[tid], red[tid + st]); __syncthreads(); }
  m = red[0]; __syncthreads();
  float e0 = __expf(s0 - m), e1 = __expf(s1 - m);
  aw[tid] = e0; aw[tid + 256] = e1;
  red[tid] = e0 + e1; __syncthreads();
  for (int st = 128; st; st >>= 1) { if (tid < st) red[tid] += red[tid + st]; __syncthreads(); }
  float inv = frcp(red[0]);
  __syncthreads();
  int wv = tid >> 6, l = tid & 63;
  int q = l & 15, tp = l >> 4;
  const unsigned short* eb = enc_bf + (size_t)b * T * H + y * 64 + q * 4;
  float a0 = 0.f, a1 = 0.f, a2 = 0.f, a3 = 0.f;
  for (int it = 0; it < 32; it++) {
    int t = it * 16 + wv * 4 + tp;
    uint2 u = *(const uint2*)&eb[(size_t)t * H];
    float w = aw[t];
    a0 += w * bf2f((unsigned short)(u.x & 0xffff));
    a1 += w * bf2f((unsigned short)(u.x >> 16));
    a2 += w * bf2f((unsigned short)(u.y & 0xffff));
    a3 += w * bf2f((unsigned short)(u.y >> 16));
  }
  a0 += __shfl_xor(a0, 16, 64); a0 += __shfl_xor(a0, 32, 64);
  a1 += __shfl_xor(a1, 16, 64); a1 += __shfl_xor(a1, 32, 64);
  a2 += __shfl_xor(a2, 16, 64); a2 += __shfl_xor(a2, 32, 64);
  a3 += __shfl_xor(a3, 16, 64); a3 += __shfl_xor(a3, 32, 64);
  __syncthreads();
  if (tp == 0) {
    red[wv * 64 + q * 4 + 0] = a0; red[wv * 64 + q * 4 + 1] = a1;
    red[wv * 64 + q * 4 + 2] = a2; red[wv * 64 + q * 4 + 3] = a3;
  }
  __syncthreads();
  if (tid < 64) {
    float val = (red[tid] + red[64 + tid] + red[128 + tid] + red[192 + tid]) * inv;
    xc[(size_t)b * K0 + E + y * 64 + tid] = f2bf(val);
  }
}

// ===== final log-softmax write (last step only) ============================
__global__ __launch_bounds__(256) void k_lsB(const float* __restrict__ logits,
    const float* __restrict__ part, float* __restrict__ out, int s) {
  int b = blockIdx.x, ch = blockIdx.y, tid = threadIdx.x;
  __shared__ float red[256];
  float ssum = 0.f;
  for (int i = tid; i < V / 64; i += 256) ssum += part[i * 32 + b];
  red[tid] = ssum; __syncthreads();
  for (int st = 128; st; st >>= 1) { if (tid < st) red[tid] += red[tid + st]; __syncthreads(); }
  float lse = __logf(red[0]);
  const float* L = logits + (size_t)b * V + ch * 4000;
  float* O = out + ((size_t)b * S + s) * V + ch * 4000;
  for (int i = tid; i < 1000; i += 256) {
    float4 v = ((const float4*)L)[i];
    ((float4*)O)[i] = make_float4(v.x - lse, v.y - lse, v.z - lse, v.w - lse);
  }
}

// ===========================================================================
extern "C" void kernel_launch(void* const* d_in, const int* in_sizes, int n_in,
                              void* d_out, int out_size, void* d_ws, size_t ws_size,
                              hipStream_t stream) {
  const float* enc_out   = (const float*)d_in[0];
  const float* enc_h     = (const float*)d_in[1];
  const float* enc_c     = (const float*)d_in[2];
  const float* embedding = (const float*)d_in[3];
  const float* attn_W    = (const float*)d_in[4];
  const float* attn_b    = (const float*)d_in[5];
  const float* vvec      = (const float*)d_in[6];
  const float* Wih0      = (const float*)d_in[7];
  const float* Whh0      = (const float*)d_in[8];
  const float* bih0      = (const float*)d_in[9];
  const float* bhh0      = (const float*)d_in[10];
  const float* Wih1      = (const float*)d_in[11];
  const float* Whh1      = (const float*)d_in[12];
  const float* bih1      = (const float*)d_in[13];
  const float* bhh1      = (const float*)d_in[14];
  const float* genW      = (const float*)d_in[15];
  const float* genb      = (const float*)d_in[16];
  const int*   question  = (const int*)d_in[17];
  float* out = (float*)d_out;

  char* w = (char*)d_ws;
  auto alloc = [&](size_t bytes) { char* r = w; w += (bytes + 255) & ~(size_t)255; return r; };
  unsigned short* Wbig  = (unsigned short*)alloc((size_t)MG * H * 2);
  unsigned short* Wc0   = (unsigned short*)alloc((size_t)4096 * K0 * 2);
  unsigned short* Wc1   = (unsigned short*)alloc((size_t)4096 * K1 * 2);
  unsigned short* encb  = (unsigned short*)alloc((size_t)B * T * H * 2);
  unsigned short* encp  = (unsigned short*)alloc((size_t)B * T * H * 2);
  unsigned short* Wr    = (unsigned short*)alloc((size_t)H * H * 2);
  float* bcomb0 = (float*)alloc(4096 * 4);
  float* bcomb1 = (float*)alloc(4096 * 4);
  float* cbuf   = (float*)alloc((size_t)2 * B * H * 4);
  unsigned short* xc0[2] = {(unsigned short*)alloc((size_t)B * K0 * 2),
                            (unsigned short*)alloc((size_t)B * K0 * 2)};
  unsigned short* xc1[2] = {(unsigned short*)alloc((size_t)B * K1 * 2),
                            (unsigned short*)alloc((size_t)B * K1 * 2)};
  unsigned short* hgen  = (unsigned short*)alloc((size_t)B * H * 2);
  float* hidproj = (float*)alloc((size_t)B * H * 4);
  float* scores  = (float*)alloc((size_t)B * T * 4);
  float* logits  = (float*)alloc((size_t)B * V * 4);
  float* part    = (float*)alloc((size_t)(V / 64) * 32 * 4);

  // one-time prep
  k_cast_gen<<<(int)(((size_t)MG * H / 4 + 255) / 256), 256, 0, stream>>>(genW, attn_W, Wbig);
  k_cast_l0<<<4096, 256, 0, stream>>>(Wih0, Whh0, Wc0);
  k_cast_l1<<<4096, 256, 0, stream>>>(Wih1, Whh1, Wc1);
  k_cast_attnr<<<H * H / 4 / 256, 256, 0, stream>>>(attn_W, Wr);
  k_bias<<<32, 256, 0, stream>>>(bih0, bhh0, bih1, bhh1, bcomb0, bcomb1);
  k_cast_enc<<<(B * T * H / 4) / 256, 256, 0, stream>>>(enc_out, encb);
  k_init<<<(2 * B * H + 2 * B * 20 + 255) / 256, 256, 0, stream>>>(
      enc_h, enc_c, cbuf, xc0[0], xc0[1], xc1[0], hgen);
  k_encproj_mfma<<<dim3(H / 64, B * T / 64), 256, 0, stream>>>(Wr, encb, attn_b, encp);
  // hidproj for step 0 from initial h1
  k_gemm_out<1024><<<H / 64, 256, 0, stream>>>(
      Wbig + (size_t)V * H, hgen, nullptr, 0, nullptr, 0, hidproj, H, nullptr);

  for (int s = 0; s < S; s++) {
    int par = s & 1;
    k_p1<<<4384, 256, 0, stream>>>(encp, hidproj, vvec, scores,
                                   logits, part, out, embedding, question, xc0[par], s);
    k_ctx<<<dim3(B, 16), 256, 0, stream>>>(scores, encb, xc0[par]);
    k_gemm_lstm<K0><<<4096 / 16, 256, 0, stream>>>(
        Wc0, xc0[par], bcomb0, cbuf,
        xc0[par ^ 1], K0, KX,        // h0n -> next step's layer-0 recurrent slot
        xc1[par], K1, 0);            // h0n -> layer-1 input slot (this step)
    k_gemm_lstm<K1><<<4096 / 16, 256, 0, stream>>>(
        Wc1, xc1[par], bcomb1, cbuf + B * H,
        xc1[par ^ 1], K1, H,         // h1n -> next step's layer-1 recurrent slot
        hgen, H, 0);                 // h1n -> generator/hidproj input
    k_gemm_out<1024><<<MG / 64, 256, 0, stream>>>(
        Wbig, hgen, genb, V, logits, V, hidproj, H, part);
  }
  k_lsB<<<dim3(B, 8), 256, 0, stream>>>(logits, part, out, S - 1);
}